// Round 3
// baseline (498.605 us; speedup 1.0000x reference)
//
#include <hip/hip_runtime.h>

// DeltaNet fused pipeline, round 2:
//   k_cast:   x fp32 -> bf16
//   k_transw: Wq/Wk/Wv -> Wt (N x K bf16), Wo -> Wot
//   k_transg: Wg -> Wgt [128][2048] bf16 (rows 16..127 zero)
//   k_gemm:   bf16 MFMA 128x128 GEMM, m97-style global_load_lds(16B) staging,
//             unpadded [128][32] LDS tiles. Used for QKV (N=6144), beta logits
//             (N=128), and out-proj.
//   k_beta2:  beta = clip(sigmoid(braw + bg))
//   k_prep:   G-scan + RoPE + phi + scale + K^T transpose + intra-chunk A (MFMA)
//   k_scan:   sequential 32-chunk scan, state in fp32 MFMA accumulators
//   k_scale:  numerb = bf16(numer * invd)   (fuses the 1/denom)
//   k_gemm:   out = numerb @ Wot + bo

typedef __attribute__((ext_vector_type(8))) short short8;
typedef __attribute__((ext_vector_type(4))) float f32x4;

__device__ __forceinline__ unsigned short f2bf(float f) {
  unsigned u = __float_as_uint(f);
  u += 0x7fffu + ((u >> 16) & 1u);   // RNE
  return (unsigned short)(u >> 16);
}
__device__ __forceinline__ float bf2f(unsigned short s) {
  return __uint_as_float(((unsigned)s) << 16);
}
__device__ __forceinline__ float phi_elu1(float x) {
  return x > 0.f ? x + 1.f : expf(x);
}
// async global->LDS, 16B per lane. LDS dest is wave-uniform base + lane*16;
// caller must arrange lane l's pointer == firstlane base + l*16.
__device__ __forceinline__ void gl_lds16(const void* g, void* l) {
  __builtin_amdgcn_global_load_lds(
      (const __attribute__((address_space(1))) void*)g,
      (__attribute__((address_space(3))) void*)l, 16, 0, 0);
}

// ---------------- cast x -> bf16 ----------------
__global__ __launch_bounds__(256)
void k_cast(const float* __restrict__ x, unsigned short* __restrict__ xb) {
  int i = (blockIdx.x * 256 + threadIdx.x) * 4;
  float4 f = *(const float4*)(x + i);
  uint2 p;
  p.x = (unsigned)f2bf(f.x) | ((unsigned)f2bf(f.y) << 16);
  p.y = (unsigned)f2bf(f.z) | ((unsigned)f2bf(f.w) << 16);
  *(uint2*)(xb + i) = p;
}

// ---------------- transpose+cast W (K x N) -> (N x K) bf16 ----------------
__global__ __launch_bounds__(256)
void k_transw(const float* __restrict__ Wq, const float* __restrict__ Wk,
              const float* __restrict__ Wv, const float* __restrict__ Wo,
              unsigned short* __restrict__ Wt, unsigned short* __restrict__ Wot) {
  const int z = blockIdx.z;
  const float* W = (z == 0) ? Wq : (z == 1) ? Wk : (z == 2) ? Wv : Wo;
  unsigned short* out = (z < 3) ? (Wt + (size_t)z * 2048 * 2048) : Wot;
  __shared__ float tile[64][65];
  const int n0 = blockIdx.x * 64;
  const int k0 = blockIdx.y * 64;
  const int tx = threadIdx.x & 63;
  const int ty = threadIdx.x >> 6;
#pragma unroll
  for (int rl = 0; rl < 16; ++rl) {
    int kk = rl * 4 + ty;
    tile[kk][tx] = W[(size_t)(k0 + kk) * 2048 + n0 + tx];
  }
  __syncthreads();
#pragma unroll
  for (int rl = 0; rl < 16; ++rl) {
    int nn = rl * 4 + ty;
    out[(size_t)(n0 + nn) * 2048 + k0 + tx] = f2bf(tile[tx][nn]);
  }
}

// ---------------- Wg (2048x16) -> Wgt (128x2048) bf16, zero-padded ----------------
__global__ __launch_bounds__(256)
void k_transg(const float* __restrict__ Wg, unsigned short* __restrict__ Wgt) {
  int idx = blockIdx.x * 256 + threadIdx.x;   // 128*2048
  int n = idx >> 11, k = idx & 2047;
  Wgt[idx] = (n < 16) ? f2bf(Wg[k * 16 + n]) : (unsigned short)0;
}

// ---------------- beta = clip(sigmoid(braw + bg)) ----------------
__global__ __launch_bounds__(256)
void k_beta2(const float* __restrict__ braw, const float* __restrict__ bg,
             float* __restrict__ beta) {
  int idx = blockIdx.x * 256 + threadIdx.x;   // 4096*16
  int m = idx >> 4, h = idx & 15;
  float v = braw[(size_t)m * 128 + h] + bg[h];
  float bv = 1.f / (1.f + expf(-v));
  beta[idx] = fminf(fmaxf(bv, 0.8f), 0.9995f);
}

// ---------------- bf16 MFMA GEMM: C[M,N] = A[M,K] @ Bt[N,K]^T ----------------
// global_load_lds staging, unpadded LDS (m97 structure).
template <bool OUT_BF16, bool ADD_BIAS>
__global__ __launch_bounds__(256)
void k_gemm(const unsigned short* __restrict__ A, const unsigned short* __restrict__ Bt,
            void* __restrict__ Cptr, const float* __restrict__ bias,
            int M, int N, int K, int ldA, int ldC) {
  __shared__ __align__(16) unsigned short As[128][32];
  __shared__ __align__(16) unsigned short Bs[128][32];
  const int tid = threadIdx.x;
  const int n0 = blockIdx.x * 128;
  const int m0 = blockIdx.y * 128;
  const int lane = tid & 63;
  const int w = tid >> 6;
  const int wm = w >> 1, wn = w & 1;
  const int q = lane >> 4, r = lane & 15;

  // staging: wave w, inst i in {0,1}: lane l -> LDS short idx w*1024+i*512+l*8
  //   row = w*32 + i*16 + (l>>2), kc = (l&3)*8  => byte off = w*2048+i*1024+l*16
  const int srow = w * 32 + (lane >> 2);
  const int skc = (lane & 3) * 8;

  f32x4 acc[4][4];
#pragma unroll
  for (int i = 0; i < 4; ++i)
#pragma unroll
    for (int j = 0; j < 4; ++j) acc[i][j] = (f32x4){0.f, 0.f, 0.f, 0.f};

  const unsigned short* Ap = A + (size_t)(m0 + srow) * ldA + skc;
  const unsigned short* Ap2 = Ap + (size_t)16 * ldA;
  const unsigned short* Bp = Bt + (size_t)(n0 + srow) * K + skc;
  const unsigned short* Bp2 = Bp + (size_t)16 * K;

  for (int kt = 0; kt < K; kt += 32) {
    __syncthreads();
    gl_lds16(Ap + kt, &As[srow][skc]);
    gl_lds16(Ap2 + kt, &As[srow + 16][skc]);
    gl_lds16(Bp + kt, &Bs[srow][skc]);
    gl_lds16(Bp2 + kt, &Bs[srow + 16][skc]);
    __syncthreads();
    short8 af[4], bfr[4];
#pragma unroll
    for (int i = 0; i < 4; ++i)
      af[i] = *(const short8*)&As[wm * 64 + i * 16 + r][q * 8];
#pragma unroll
    for (int j = 0; j < 4; ++j)
      bfr[j] = *(const short8*)&Bs[wn * 64 + j * 16 + r][q * 8];
#pragma unroll
    for (int i = 0; i < 4; ++i)
#pragma unroll
      for (int j = 0; j < 4; ++j)
        acc[i][j] = __builtin_amdgcn_mfma_f32_16x16x32_bf16(af[i], bfr[j], acc[i][j], 0, 0, 0);
  }
#pragma unroll
  for (int i = 0; i < 4; ++i) {
#pragma unroll
    for (int j = 0; j < 4; ++j) {
#pragma unroll
      for (int rr = 0; rr < 4; ++rr) {
        int mi = m0 + wm * 64 + i * 16 + q * 4 + rr;
        int ni = n0 + wn * 64 + j * 16 + r;
        float val = acc[i][j][rr];
        if (ADD_BIAS) val += bias[ni];
        if (OUT_BF16)
          ((unsigned short*)Cptr)[(size_t)mi * ldC + ni] = f2bf(val);
        else
          ((float*)Cptr)[(size_t)mi * ldC + ni] = val;
      }
    }
  }
}

// ---------------- prep: G-scan + RoPE + phi + scale + transpose + intra-chunk A ----------------
__global__ __launch_bounds__(256)
void k_prep(const unsigned short* __restrict__ qkv, const float* __restrict__ beta,
            unsigned short* __restrict__ Qt, unsigned short* __restrict__ Ktg,
            unsigned short* __restrict__ Ag) {
  const int ch = blockIdx.x;
  const int bh = blockIdx.y;
  const int b = bh >> 4, h = bh & 15;
  const int tid = threadIdx.x;
  const int t0 = ch * 64;

  __shared__ float Gs[64];
  __shared__ unsigned short Qs[64][136];
  __shared__ unsigned short Ks[64][136];

  if (tid < 64) {
    float bb = beta[((size_t)(b * 2048 + t0 + tid)) * 16 + h];
#pragma unroll
    for (int off = 1; off < 64; off <<= 1) {
      float o = __shfl_up(bb, off, 64);
      if (tid >= off) bb *= o;
    }
    Gs[tid] = bb;
  }
  __syncthreads();

  const int dgl = tid & 7;
  float invf[8];
#pragma unroll
  for (int j = 0; j < 8; ++j)
    invf[j] = expf((float)(dgl * 8 + j) * -0.14391156831212787f);  // 10000^(-e/64)

  int s = tid >> 3;
#pragma unroll
  for (int rep = 0; rep < 2; ++rep, s += 32) {
    size_t row = ((size_t)(b * 2048 + t0 + s)) * 6144 + (size_t)h * 128;
    short8 qlo = *(const short8*)(qkv + row + dgl * 8);
    short8 qhi = *(const short8*)(qkv + row + 64 + dgl * 8);
    short8 klo = *(const short8*)(qkv + row + 2048 + dgl * 8);
    short8 khi = *(const short8*)(qkv + row + 2048 + 64 + dgl * 8);
    float g = Gs[s];
    float ig = 1.f / g;
    float tg = (float)(t0 + s);
    short8 oql, oqh, okl, okh;
#pragma unroll
    for (int j = 0; j < 8; ++j) {
      float sn, cs;
      __sincosf(tg * invf[j], &sn, &cs);
      float qe = bf2f((unsigned short)qlo[j]), qo = bf2f((unsigned short)qhi[j]);
      float a0 = qe * cs - qo * sn, a1 = qe * sn + qo * cs;
      oql[j] = (short)f2bf(phi_elu1(a0) * g);
      oqh[j] = (short)f2bf(phi_elu1(a1) * g);
      float ke = bf2f((unsigned short)klo[j]), ko = bf2f((unsigned short)khi[j]);
      a0 = ke * cs - ko * sn;
      a1 = ke * sn + ko * cs;
      okl[j] = (short)f2bf(phi_elu1(a0) * ig);
      okh[j] = (short)f2bf(phi_elu1(a1) * ig);
    }
    size_t qbase = (((size_t)bh * 32 + ch) * 64 + s) * 128;
    *(short8*)(Qt + qbase + dgl * 8) = oql;
    *(short8*)(Qt + qbase + 64 + dgl * 8) = oqh;
    *(short8*)&Qs[s][dgl * 8] = oql;
    *(short8*)&Qs[s][64 + dgl * 8] = oqh;
    *(short8*)&Ks[s][dgl * 8] = okl;
    *(short8*)&Ks[s][64 + dgl * 8] = okh;
  }
  __syncthreads();

  {
    const int d = tid >> 1, sh = tid & 1;
    unsigned pk[16];
#pragma unroll
    for (int i = 0; i < 16; ++i)
      pk[i] = (unsigned)Ks[sh * 32 + 2 * i][d] | ((unsigned)Ks[sh * 32 + 2 * i + 1][d] << 16);
    unsigned short* kr = Ktg + ((size_t)bh * 32 + ch) * 8192 + (size_t)d * 64 + sh * 32;
#pragma unroll
    for (int i = 0; i < 4; ++i)
      *(uint4*)(kr + i * 8) = *(uint4*)&pk[i * 4];
  }

  {
    const int lane = tid & 63;
    const int w = tid >> 6;
    const int q = lane >> 4, r = lane & 15;
    f32x4 acc[4];
#pragma unroll
    for (int nt = 0; nt < 4; ++nt) acc[nt] = (f32x4){0.f, 0.f, 0.f, 0.f};
#pragma unroll
    for (int kk = 0; kk < 4; ++kk) {
      short8 af = *(const short8*)&Qs[w * 16 + r][kk * 32 + q * 8];
#pragma unroll
      for (int nt = 0; nt < 4; ++nt) {
        short8 bf = *(const short8*)&Ks[nt * 16 + r][kk * 32 + q * 8];
        acc[nt] = __builtin_amdgcn_mfma_f32_16x16x32_bf16(af, bf, acc[nt], 0, 0, 0);
      }
    }
    unsigned short* Agp = Ag + ((size_t)bh * 32 + ch) * 4096;
#pragma unroll
    for (int nt = 0; nt < 4; ++nt) {
#pragma unroll
      for (int rr = 0; rr < 4; ++rr) {
        int t_l = w * 16 + q * 4 + rr;
        int s_l = nt * 16 + r;
        float val = (s_l <= t_l) ? acc[nt][rr] : 0.f;
        Agp[t_l * 64 + s_l] = f2bf(val);
      }
    }
  }
}

// ---------------- chunk scan ----------------
__global__ __launch_bounds__(256)
void k_scan(const unsigned short* __restrict__ Qt, const unsigned short* __restrict__ Ktg,
            const unsigned short* __restrict__ Ag, const unsigned short* __restrict__ qkv,
            const float* __restrict__ beta, float* __restrict__ numer,
            float* __restrict__ invd) {
  const int eb = blockIdx.x;
  const int bh = blockIdx.y;
  const int b = bh >> 4, h = bh & 15;
  const int tid = threadIdx.x;
  const int lane = tid & 63;
  const int w = tid >> 6;
  const int q = lane >> 4, r = lane & 15;
  const int e0 = eb * 16;

  __shared__ unsigned short Qs[64][136];
  __shared__ unsigned short Kts[128][72];
  __shared__ unsigned short As[64][72];
  __shared__ unsigned short Vt[16][72];
  __shared__ unsigned short Sb[128][18];

  f32x4 S_acc[2];
  S_acc[0] = (f32x4){0.f, 0.f, 0.f, 0.f};
  S_acc[1] = (f32x4){0.f, 0.f, 0.f, 0.f};

  for (int ch = 0; ch < 32; ++ch) {
    __syncthreads();
    {
      const unsigned short* Qg = Qt + ((size_t)bh * 32 + ch) * 8192;
#pragma unroll
      for (int i = 0; i < 4; ++i) {
        int c = tid + i * 256;
        int ss = c >> 4, dg = c & 15;
        *(int4*)&Qs[ss][dg * 8] = *(const int4*)(Qg + ss * 128 + dg * 8);
      }
      const unsigned short* Kg = Ktg + ((size_t)bh * 32 + ch) * 8192;
#pragma unroll
      for (int i = 0; i < 4; ++i) {
        int c = tid + i * 256;
        int d = c >> 3, sg = c & 7;
        *(int4*)&Kts[d][sg * 8] = *(const int4*)(Kg + d * 64 + sg * 8);
      }
      const unsigned short* Agp = Ag + ((size_t)bh * 32 + ch) * 4096;
#pragma unroll
      for (int i = 0; i < 2; ++i) {
        int c = tid + i * 256;
        int t_l = c >> 3, sg = c & 7;
        *(int4*)&As[t_l][sg * 8] = *(const int4*)(Agp + t_l * 64 + sg * 8);
      }
      if (eb < 8) {
        int ss = tid >> 2, e4 = tid & 3;
        const unsigned short* vp =
            qkv + ((size_t)(b * 2048 + ch * 64 + ss)) * 6144 + 4096 + h * 128 + e0 + e4 * 4;
        uint2 vv = *(const uint2*)vp;
        const unsigned short* pv = (const unsigned short*)&vv;
#pragma unroll
        for (int j = 0; j < 4; ++j) Vt[e4 * 4 + j][ss] = pv[j];
      } else {
        int e = tid >> 4, s4 = (tid & 15) * 4;
#pragma unroll
        for (int j = 0; j < 4; ++j) Vt[e][s4 + j] = (e == 0) ? (unsigned short)0x3F80 : (unsigned short)0;
      }
#pragma unroll
      for (int i = 0; i < 2; ++i)
#pragma unroll
        for (int rr = 0; rr < 4; ++rr)
          Sb[(2 * w + i) * 16 + q * 4 + rr][r] = f2bf(S_acc[i][rr]);
    }
    __syncthreads();

    float gc;
    {
      float bl = beta[((size_t)(b * 2048 + ch * 64 + lane)) * 16 + h];
#pragma unroll
      for (int off = 1; off < 64; off <<= 1) bl *= __shfl_xor(bl, off, 64);
      gc = bl;
    }

    f32x4 nacc = (f32x4){0.f, 0.f, 0.f, 0.f};
#pragma unroll
    for (int kk = 0; kk < 4; ++kk) {
      short8 af = *(const short8*)&Qs[w * 16 + r][kk * 32 + q * 8];
      short8 bf;
#pragma unroll
      for (int j = 0; j < 8; ++j) bf[j] = (short)Sb[kk * 32 + q * 8 + j][r];
      nacc = __builtin_amdgcn_mfma_f32_16x16x32_bf16(af, bf, nacc, 0, 0, 0);
    }
    short8 vf[2];
#pragma unroll
    for (int kk = 0; kk < 2; ++kk) {
      vf[kk] = *(const short8*)&Vt[r][kk * 32 + q * 8];
      short8 af = *(const short8*)&As[w * 16 + r][kk * 32 + q * 8];
      nacc = __builtin_amdgcn_mfma_f32_16x16x32_bf16(af, vf[kk], nacc, 0, 0, 0);
    }
#pragma unroll
    for (int rr = 0; rr < 4; ++rr) {
      int t_l = w * 16 + q * 4 + rr;
      size_t m = (size_t)b * 2048 + ch * 64 + t_l;
      if (eb < 8)
        numer[m * 2048 + h * 128 + e0 + r] = nacc[rr];
      else if (r == 0)
        invd[m * 16 + h] = 1.f / (nacc[rr] + 1e-6f);
    }

#pragma unroll
    for (int i = 0; i < 2; ++i) {
#pragma unroll
      for (int kk = 0; kk < 2; ++kk) {
        short8 af = *(const short8*)&Kts[(2 * w + i) * 16 + r][kk * 32 + q * 8];
        S_acc[i] = __builtin_amdgcn_mfma_f32_16x16x32_bf16(af, vf[kk], S_acc[i], 0, 0, 0);
      }
#pragma unroll
      for (int rr = 0; rr < 4; ++rr) S_acc[i][rr] *= gc;
    }
  }
}

// ---------------- numerb = bf16(numer * invd) ----------------
__global__ __launch_bounds__(256)
void k_scale(const float* __restrict__ numer, const float* __restrict__ invd,
             unsigned short* __restrict__ nb) {
  int base = (blockIdx.x * 256 + threadIdx.x) * 8;
  int m = base >> 11;
  int h = (base & 2047) >> 7;
  float sc = invd[(size_t)m * 16 + h];
  float4 a = *(const float4*)(numer + base);
  float4 b = *(const float4*)(numer + base + 4);
  uint2 p0, p1;
  p0.x = (unsigned)f2bf(a.x * sc) | ((unsigned)f2bf(a.y * sc) << 16);
  p0.y = (unsigned)f2bf(a.z * sc) | ((unsigned)f2bf(a.w * sc) << 16);
  p1.x = (unsigned)f2bf(b.x * sc) | ((unsigned)f2bf(b.y * sc) << 16);
  p1.y = (unsigned)f2bf(b.z * sc) | ((unsigned)f2bf(b.w * sc) << 16);
  *(uint2*)(nb + base) = p0;
  *(uint2*)(nb + base + 4) = p1;
}

extern "C" void kernel_launch(void* const* d_in, const int* in_sizes, int n_in,
                              void* d_out, int out_size, void* d_ws, size_t ws_size,
                              hipStream_t stream) {
  const float* x  = (const float*)d_in[0];
  const float* Wq = (const float*)d_in[1];
  const float* Wk = (const float*)d_in[2];
  const float* Wv = (const float*)d_in[3];
  const float* Wg = (const float*)d_in[4];
  const float* bg = (const float*)d_in[5];
  const float* Wo = (const float*)d_in[6];
  const float* bo = (const float*)d_in[7];

  // workspace layout (bytes), total 134,742,016 (unchanged from validated R0)
  char* ws = (char*)d_ws;
  unsigned short* xb    = (unsigned short*)(ws);             // 16.7MB: xb -> Qt -> numerb
  unsigned short* Qt    = (unsigned short*)(ws);
  unsigned short* numerb= (unsigned short*)(ws);
  unsigned short* Wt    = (unsigned short*)(ws + 16777216);  // 25.2MB: Wt -> Ktg+Ag
  unsigned short* Ktg   = (unsigned short*)(ws + 16777216);
  unsigned short* Ag    = (unsigned short*)(ws + 33554432);
  unsigned short* Wot   = (unsigned short*)(ws + 41943040);  //  8.4MB
  unsigned short* qkvb  = (unsigned short*)(ws + 50331648);  // 50.3MB
  float*          beta  = (float*)(ws + 100663296);          //  0.26MB
  float*          invd  = (float*)(ws + 100925440);          //  0.26MB
  float*          numer = (float*)(ws + 101187584);          // 33.6MB (scan onward)
  unsigned short* Wgt   = (unsigned short*)(ws + 101187584); //  0.5MB (dead before scan)
  float*          braw  = (float*)(ws + 101187584 + 524288); //  2.1MB (dead before scan)

  k_cast<<<8192, 256, 0, stream>>>(x, xb);
  k_transw<<<dim3(32, 32, 4), 256, 0, stream>>>(Wq, Wk, Wv, Wo, Wt, Wot);
  k_transg<<<1024, 256, 0, stream>>>(Wg, Wgt);
  k_gemm<true, false><<<dim3(48, 32), 256, 0, stream>>>(
      xb, Wt, qkvb, nullptr, 4096, 6144, 2048, 2048, 6144);
  k_gemm<false, false><<<dim3(1, 32), 256, 0, stream>>>(
      xb, Wgt, braw, nullptr, 4096, 128, 2048, 2048, 128);
  k_beta2<<<256, 256, 0, stream>>>(braw, bg, beta);
  k_prep<<<dim3(32, 32), 256, 0, stream>>>(qkvb, beta, Qt, Ktg, Ag);
  k_scan<<<dim3(9, 32), 256, 0, stream>>>(Qt, Ktg, Ag, qkvb, beta, numer, invd);
  k_scale<<<4096, 256, 0, stream>>>(numer, invd, numerb);
  k_gemm<false, true><<<dim3(16, 32), 256, 0, stream>>>(
      numerb, Wot, d_out, bo, 4096, 2048, 2048, 2048, 2048);
}

// Round 4
// 477.617 us; speedup vs baseline: 1.0439x; 1.0439x over previous
//
#include <hip/hip_runtime.h>

// DeltaNet fused pipeline, round 4:
//   k_cast:     x fp32 -> bf16
//   k_transw:   Wq/Wk/Wv -> Wt (N x K bf16), Wo -> Wot
//   k_transg16: Wg -> Wgt16 [16][2048] bf16
//   k_gemm:     bf16 MFMA 128x128 GEMM, global_load_lds(16B) staging (QKV, out)
//   k_betaW:    wave-per-row dot: beta = clip(sigmoid(xb . Wgt16[h] + bg))
//   k_prep:     G-scan + RoPE + phi + scale + K^T transpose + intra-chunk A;
//               also writes gchunk[bh][ch] = prod(beta over chunk)
//   k_scan:     sequential 32-chunk scan, state in fp32 MFMA accumulators;
//               SbT-transposed state readout (vector LDS reads), gchunk decay
//   k_scale:    numerb = bf16(numer * invd)
//   k_gemm:     out = numerb @ Wot + bo

typedef __attribute__((ext_vector_type(8))) short short8;
typedef __attribute__((ext_vector_type(4))) float f32x4;

__device__ __forceinline__ unsigned short f2bf(float f) {
  unsigned u = __float_as_uint(f);
  u += 0x7fffu + ((u >> 16) & 1u);   // RNE
  return (unsigned short)(u >> 16);
}
__device__ __forceinline__ float bf2f(unsigned short s) {
  return __uint_as_float(((unsigned)s) << 16);
}
__device__ __forceinline__ float phi_elu1(float x) {
  return x > 0.f ? x + 1.f : expf(x);
}
// async global->LDS, 16B per lane; LDS dest = wave-uniform base + lane*16.
__device__ __forceinline__ void gl_lds16(const void* g, void* l) {
  __builtin_amdgcn_global_load_lds(
      (const __attribute__((address_space(1))) void*)g,
      (__attribute__((address_space(3))) void*)l, 16, 0, 0);
}

// ---------------- cast x -> bf16 ----------------
__global__ __launch_bounds__(256)
void k_cast(const float* __restrict__ x, unsigned short* __restrict__ xb) {
  int i = (blockIdx.x * 256 + threadIdx.x) * 4;
  float4 f = *(const float4*)(x + i);
  uint2 p;
  p.x = (unsigned)f2bf(f.x) | ((unsigned)f2bf(f.y) << 16);
  p.y = (unsigned)f2bf(f.z) | ((unsigned)f2bf(f.w) << 16);
  *(uint2*)(xb + i) = p;
}

// ---------------- transpose+cast W (K x N) -> (N x K) bf16 ----------------
__global__ __launch_bounds__(256)
void k_transw(const float* __restrict__ Wq, const float* __restrict__ Wk,
              const float* __restrict__ Wv, const float* __restrict__ Wo,
              unsigned short* __restrict__ Wt, unsigned short* __restrict__ Wot) {
  const int z = blockIdx.z;
  const float* W = (z == 0) ? Wq : (z == 1) ? Wk : (z == 2) ? Wv : Wo;
  unsigned short* out = (z < 3) ? (Wt + (size_t)z * 2048 * 2048) : Wot;
  __shared__ float tile[64][65];
  const int n0 = blockIdx.x * 64;
  const int k0 = blockIdx.y * 64;
  const int tx = threadIdx.x & 63;
  const int ty = threadIdx.x >> 6;
#pragma unroll
  for (int rl = 0; rl < 16; ++rl) {
    int kk = rl * 4 + ty;
    tile[kk][tx] = W[(size_t)(k0 + kk) * 2048 + n0 + tx];
  }
  __syncthreads();
#pragma unroll
  for (int rl = 0; rl < 16; ++rl) {
    int nn = rl * 4 + ty;
    out[(size_t)(n0 + nn) * 2048 + k0 + tx] = f2bf(tile[tx][nn]);
  }
}

// ---------------- Wg (2048x16) -> Wgt16 (16x2048) bf16 ----------------
__global__ __launch_bounds__(256)
void k_transg16(const float* __restrict__ Wg, unsigned short* __restrict__ Wgt16) {
  int idx = blockIdx.x * 256 + threadIdx.x;  // 16*2048
  int h = idx >> 11, k = idx & 2047;
  Wgt16[idx] = f2bf(Wg[k * 16 + h]);
}

// ---------------- beta: wave-per-row bf16 dot + sigmoid + clip ----------------
__global__ __launch_bounds__(256)
void k_betaW(const unsigned short* __restrict__ xb, const unsigned short* __restrict__ Wgt16,
             const float* __restrict__ bg, float* __restrict__ beta) {
  const int w = threadIdx.x >> 6;
  const int lane = threadIdx.x & 63;
  const int m = blockIdx.x * 4 + w;
  const int h = lane & 15, kq = lane >> 4;
  const unsigned short* xr = xb + (size_t)m * 2048 + kq * 512;
  const unsigned short* wr = Wgt16 + (size_t)h * 2048 + kq * 512;
  float acc = 0.f;
#pragma unroll 8
  for (int i = 0; i < 64; ++i) {
    short8 xv = *(const short8*)(xr + i * 8);
    short8 wv = *(const short8*)(wr + i * 8);
#pragma unroll
    for (int j = 0; j < 8; ++j)
      acc = fmaf(bf2f((unsigned short)xv[j]), bf2f((unsigned short)wv[j]), acc);
  }
  acc += __shfl_xor(acc, 16, 64);
  acc += __shfl_xor(acc, 32, 64);
  if (lane < 16) {
    float v = acc + bg[h];
    float bv = 1.f / (1.f + expf(-v));
    beta[(size_t)m * 16 + h] = fminf(fmaxf(bv, 0.8f), 0.9995f);
  }
}

// ---------------- bf16 MFMA GEMM: C[M,N] = A[M,K] @ Bt[N,K]^T ----------------
template <bool OUT_BF16, bool ADD_BIAS>
__global__ __launch_bounds__(256)
void k_gemm(const unsigned short* __restrict__ A, const unsigned short* __restrict__ Bt,
            void* __restrict__ Cptr, const float* __restrict__ bias,
            int M, int N, int K, int ldA, int ldC) {
  __shared__ __align__(16) unsigned short As[128][32];
  __shared__ __align__(16) unsigned short Bs[128][32];
  const int tid = threadIdx.x;
  const int n0 = blockIdx.x * 128;
  const int m0 = blockIdx.y * 128;
  const int lane = tid & 63;
  const int w = tid >> 6;
  const int wm = w >> 1, wn = w & 1;
  const int q = lane >> 4, r = lane & 15;

  const int srow = w * 32 + (lane >> 2);
  const int skc = (lane & 3) * 8;

  f32x4 acc[4][4];
#pragma unroll
  for (int i = 0; i < 4; ++i)
#pragma unroll
    for (int j = 0; j < 4; ++j) acc[i][j] = (f32x4){0.f, 0.f, 0.f, 0.f};

  const unsigned short* Ap = A + (size_t)(m0 + srow) * ldA + skc;
  const unsigned short* Ap2 = Ap + (size_t)16 * ldA;
  const unsigned short* Bp = Bt + (size_t)(n0 + srow) * K + skc;
  const unsigned short* Bp2 = Bp + (size_t)16 * K;

  for (int kt = 0; kt < K; kt += 32) {
    __syncthreads();
    gl_lds16(Ap + kt, &As[srow][skc]);
    gl_lds16(Ap2 + kt, &As[srow + 16][skc]);
    gl_lds16(Bp + kt, &Bs[srow][skc]);
    gl_lds16(Bp2 + kt, &Bs[srow + 16][skc]);
    __syncthreads();
    short8 af[4], bfr[4];
#pragma unroll
    for (int i = 0; i < 4; ++i)
      af[i] = *(const short8*)&As[wm * 64 + i * 16 + r][q * 8];
#pragma unroll
    for (int j = 0; j < 4; ++j)
      bfr[j] = *(const short8*)&Bs[wn * 64 + j * 16 + r][q * 8];
#pragma unroll
    for (int i = 0; i < 4; ++i)
#pragma unroll
      for (int j = 0; j < 4; ++j)
        acc[i][j] = __builtin_amdgcn_mfma_f32_16x16x32_bf16(af[i], bfr[j], acc[i][j], 0, 0, 0);
  }
#pragma unroll
  for (int i = 0; i < 4; ++i) {
#pragma unroll
    for (int j = 0; j < 4; ++j) {
#pragma unroll
      for (int rr = 0; rr < 4; ++rr) {
        int mi = m0 + wm * 64 + i * 16 + q * 4 + rr;
        int ni = n0 + wn * 64 + j * 16 + r;
        float val = acc[i][j][rr];
        if (ADD_BIAS) val += bias[ni];
        if (OUT_BF16)
          ((unsigned short*)Cptr)[(size_t)mi * ldC + ni] = f2bf(val);
        else
          ((float*)Cptr)[(size_t)mi * ldC + ni] = val;
      }
    }
  }
}

// ---------------- prep: G-scan + RoPE + phi + scale + transpose + intra-chunk A ----------------
__global__ __launch_bounds__(256)
void k_prep(const unsigned short* __restrict__ qkv, const float* __restrict__ beta,
            unsigned short* __restrict__ Qt, unsigned short* __restrict__ Ktg,
            unsigned short* __restrict__ Ag, float* __restrict__ gch) {
  const int ch = blockIdx.x;
  const int bh = blockIdx.y;
  const int b = bh >> 4, h = bh & 15;
  const int tid = threadIdx.x;
  const int t0 = ch * 64;

  __shared__ float Gs[64];
  __shared__ unsigned short Qs[64][136];
  __shared__ unsigned short Ks[64][136];

  if (tid < 64) {
    float bb = beta[((size_t)(b * 2048 + t0 + tid)) * 16 + h];
#pragma unroll
    for (int off = 1; off < 64; off <<= 1) {
      float o = __shfl_up(bb, off, 64);
      if (tid >= off) bb *= o;
    }
    Gs[tid] = bb;
    if (tid == 63) gch[bh * 32 + ch] = bb;  // full-chunk decay product
  }
  __syncthreads();

  const int dgl = tid & 7;
  float invf[8];
#pragma unroll
  for (int j = 0; j < 8; ++j)
    invf[j] = expf((float)(dgl * 8 + j) * -0.14391156831212787f);  // 10000^(-e/64)

  int s = tid >> 3;
#pragma unroll
  for (int rep = 0; rep < 2; ++rep, s += 32) {
    size_t row = ((size_t)(b * 2048 + t0 + s)) * 6144 + (size_t)h * 128;
    short8 qlo = *(const short8*)(qkv + row + dgl * 8);
    short8 qhi = *(const short8*)(qkv + row + 64 + dgl * 8);
    short8 klo = *(const short8*)(qkv + row + 2048 + dgl * 8);
    short8 khi = *(const short8*)(qkv + row + 2048 + 64 + dgl * 8);
    float g = Gs[s];
    float ig = 1.f / g;
    float tg = (float)(t0 + s);
    short8 oql, oqh, okl, okh;
#pragma unroll
    for (int j = 0; j < 8; ++j) {
      float sn, cs;
      __sincosf(tg * invf[j], &sn, &cs);
      float qe = bf2f((unsigned short)qlo[j]), qo = bf2f((unsigned short)qhi[j]);
      float a0 = qe * cs - qo * sn, a1 = qe * sn + qo * cs;
      oql[j] = (short)f2bf(phi_elu1(a0) * g);
      oqh[j] = (short)f2bf(phi_elu1(a1) * g);
      float ke = bf2f((unsigned short)klo[j]), ko = bf2f((unsigned short)khi[j]);
      a0 = ke * cs - ko * sn;
      a1 = ke * sn + ko * cs;
      okl[j] = (short)f2bf(phi_elu1(a0) * ig);
      okh[j] = (short)f2bf(phi_elu1(a1) * ig);
    }
    size_t qbase = (((size_t)bh * 32 + ch) * 64 + s) * 128;
    *(short8*)(Qt + qbase + dgl * 8) = oql;
    *(short8*)(Qt + qbase + 64 + dgl * 8) = oqh;
    *(short8*)&Qs[s][dgl * 8] = oql;
    *(short8*)&Qs[s][64 + dgl * 8] = oqh;
    *(short8*)&Ks[s][dgl * 8] = okl;
    *(short8*)&Ks[s][64 + dgl * 8] = okh;
  }
  __syncthreads();

  {
    const int d = tid >> 1, sh = tid & 1;
    unsigned pk[16];
#pragma unroll
    for (int i = 0; i < 16; ++i)
      pk[i] = (unsigned)Ks[sh * 32 + 2 * i][d] | ((unsigned)Ks[sh * 32 + 2 * i + 1][d] << 16);
    unsigned short* kr = Ktg + ((size_t)bh * 32 + ch) * 8192 + (size_t)d * 64 + sh * 32;
#pragma unroll
    for (int i = 0; i < 4; ++i)
      *(uint4*)(kr + i * 8) = *(uint4*)&pk[i * 4];
  }

  {
    const int lane = tid & 63;
    const int w = tid >> 6;
    const int q = lane >> 4, r = lane & 15;
    f32x4 acc[4];
#pragma unroll
    for (int nt = 0; nt < 4; ++nt) acc[nt] = (f32x4){0.f, 0.f, 0.f, 0.f};
#pragma unroll
    for (int kk = 0; kk < 4; ++kk) {
      short8 af = *(const short8*)&Qs[w * 16 + r][kk * 32 + q * 8];
#pragma unroll
      for (int nt = 0; nt < 4; ++nt) {
        short8 bf = *(const short8*)&Ks[nt * 16 + r][kk * 32 + q * 8];
        acc[nt] = __builtin_amdgcn_mfma_f32_16x16x32_bf16(af, bf, acc[nt], 0, 0, 0);
      }
    }
    unsigned short* Agp = Ag + ((size_t)bh * 32 + ch) * 4096;
#pragma unroll
    for (int nt = 0; nt < 4; ++nt) {
#pragma unroll
      for (int rr = 0; rr < 4; ++rr) {
        int t_l = w * 16 + q * 4 + rr;
        int s_l = nt * 16 + r;
        float val = (s_l <= t_l) ? acc[nt][rr] : 0.f;
        Agp[t_l * 64 + s_l] = f2bf(val);
      }
    }
  }
}

// ---------------- chunk scan ----------------
__global__ __launch_bounds__(256)
void k_scan(const unsigned short* __restrict__ Qt, const unsigned short* __restrict__ Ktg,
            const unsigned short* __restrict__ Ag, const unsigned short* __restrict__ qkv,
            const float* __restrict__ gch, float* __restrict__ numer,
            float* __restrict__ invd) {
  const int eb = blockIdx.x;
  const int bh = blockIdx.y;
  const int b = bh >> 4, h = bh & 15;
  const int tid = threadIdx.x;
  const int lane = tid & 63;
  const int w = tid >> 6;
  const int q = lane >> 4, r = lane & 15;
  const int e0 = eb * 16;

  __shared__ unsigned short Qs[64][136];
  __shared__ unsigned short Kts[128][72];
  __shared__ unsigned short As[64][72];
  __shared__ unsigned short Vt[16][72];
  __shared__ unsigned short SbT[16][136];  // state readout, transposed [e][d]

  f32x4 S_acc[2];
  S_acc[0] = (f32x4){0.f, 0.f, 0.f, 0.f};
  S_acc[1] = (f32x4){0.f, 0.f, 0.f, 0.f};

  for (int ch = 0; ch < 32; ++ch) {
    __syncthreads();
    {
      const unsigned short* Qg = Qt + ((size_t)bh * 32 + ch) * 8192;
#pragma unroll
      for (int i = 0; i < 4; ++i) {
        int c = tid + i * 256;
        int ss = c >> 4, dg = c & 15;
        *(int4*)&Qs[ss][dg * 8] = *(const int4*)(Qg + ss * 128 + dg * 8);
      }
      const unsigned short* Kg = Ktg + ((size_t)bh * 32 + ch) * 8192;
#pragma unroll
      for (int i = 0; i < 4; ++i) {
        int c = tid + i * 256;
        int d = c >> 3, sg = c & 7;
        *(int4*)&Kts[d][sg * 8] = *(const int4*)(Kg + d * 64 + sg * 8);
      }
      const unsigned short* Agp = Ag + ((size_t)bh * 32 + ch) * 4096;
#pragma unroll
      for (int i = 0; i < 2; ++i) {
        int c = tid + i * 256;
        int t_l = c >> 3, sg = c & 7;
        *(int4*)&As[t_l][sg * 8] = *(const int4*)(Agp + t_l * 64 + sg * 8);
      }
      if (eb < 8) {
        int ss = tid >> 2, e4 = tid & 3;
        const unsigned short* vp =
            qkv + ((size_t)(b * 2048 + ch * 64 + ss)) * 6144 + 4096 + h * 128 + e0 + e4 * 4;
        uint2 vv = *(const uint2*)vp;
        const unsigned short* pv = (const unsigned short*)&vv;
#pragma unroll
        for (int j = 0; j < 4; ++j) Vt[e4 * 4 + j][ss] = pv[j];
      } else {
        int e = tid >> 4, s4 = (tid & 15) * 4;
#pragma unroll
        for (int j = 0; j < 4; ++j) Vt[e][s4 + j] = (e == 0) ? (unsigned short)0x3F80 : (unsigned short)0;
      }
      // state S0 -> bf16, transposed: SbT[e=r][d]
#pragma unroll
      for (int i = 0; i < 2; ++i)
#pragma unroll
        for (int rr = 0; rr < 4; ++rr)
          SbT[r][(2 * w + i) * 16 + q * 4 + rr] = f2bf(S_acc[i][rr]);
    }
    __syncthreads();

    const float gc = gch[bh * 32 + ch];

    // numer rows w*16..w*16+15: Qt @ S0 + A @ V
    f32x4 nacc = (f32x4){0.f, 0.f, 0.f, 0.f};
#pragma unroll
    for (int kk = 0; kk < 4; ++kk) {
      short8 af = *(const short8*)&Qs[w * 16 + r][kk * 32 + q * 8];
      short8 bf = *(const short8*)&SbT[r][kk * 32 + q * 8];
      nacc = __builtin_amdgcn_mfma_f32_16x16x32_bf16(af, bf, nacc, 0, 0, 0);
    }
    short8 vf[2];
#pragma unroll
    for (int kk = 0; kk < 2; ++kk) {
      vf[kk] = *(const short8*)&Vt[r][kk * 32 + q * 8];
      short8 af = *(const short8*)&As[w * 16 + r][kk * 32 + q * 8];
      nacc = __builtin_amdgcn_mfma_f32_16x16x32_bf16(af, vf[kk], nacc, 0, 0, 0);
    }
#pragma unroll
    for (int rr = 0; rr < 4; ++rr) {
      int t_l = w * 16 + q * 4 + rr;
      size_t m = (size_t)b * 2048 + ch * 64 + t_l;
      if (eb < 8)
        numer[m * 2048 + h * 128 + e0 + r] = nacc[rr];
      else if (r == 0)
        invd[m * 16 + h] = 1.f / (nacc[rr] + 1e-6f);
    }

    // state update: S = gc * (S0 + Kt^T V)
#pragma unroll
    for (int i = 0; i < 2; ++i) {
#pragma unroll
      for (int kk = 0; kk < 2; ++kk) {
        short8 af = *(const short8*)&Kts[(2 * w + i) * 16 + r][kk * 32 + q * 8];
        S_acc[i] = __builtin_amdgcn_mfma_f32_16x16x32_bf16(af, vf[kk], S_acc[i], 0, 0, 0);
      }
#pragma unroll
      for (int rr = 0; rr < 4; ++rr) S_acc[i][rr] *= gc;
    }
  }
}

// ---------------- numerb = bf16(numer * invd) ----------------
__global__ __launch_bounds__(256)
void k_scale(const float* __restrict__ numer, const float* __restrict__ invd,
             unsigned short* __restrict__ nb) {
  int base = (blockIdx.x * 256 + threadIdx.x) * 8;
  int m = base >> 11;
  int h = (base & 2047) >> 7;
  float sc = invd[(size_t)m * 16 + h];
  float4 a = *(const float4*)(numer + base);
  float4 b = *(const float4*)(numer + base + 4);
  uint2 p0, p1;
  p0.x = (unsigned)f2bf(a.x * sc) | ((unsigned)f2bf(a.y * sc) << 16);
  p0.y = (unsigned)f2bf(a.z * sc) | ((unsigned)f2bf(a.w * sc) << 16);
  p1.x = (unsigned)f2bf(b.x * sc) | ((unsigned)f2bf(b.y * sc) << 16);
  p1.y = (unsigned)f2bf(b.z * sc) | ((unsigned)f2bf(b.w * sc) << 16);
  *(uint2*)(nb + base) = p0;
  *(uint2*)(nb + base + 4) = p1;
}

extern "C" void kernel_launch(void* const* d_in, const int* in_sizes, int n_in,
                              void* d_out, int out_size, void* d_ws, size_t ws_size,
                              hipStream_t stream) {
  const float* x  = (const float*)d_in[0];
  const float* Wq = (const float*)d_in[1];
  const float* Wk = (const float*)d_in[2];
  const float* Wv = (const float*)d_in[3];
  const float* Wg = (const float*)d_in[4];
  const float* bg = (const float*)d_in[5];
  const float* Wo = (const float*)d_in[6];
  const float* bo = (const float*)d_in[7];

  // workspace layout (bytes), total 134,742,016 (unchanged)
  char* ws = (char*)d_ws;
  unsigned short* xb    = (unsigned short*)(ws);             // 16.7MB: xb -> Qt -> numerb
  unsigned short* Qt    = (unsigned short*)(ws);
  unsigned short* numerb= (unsigned short*)(ws);
  unsigned short* Wt    = (unsigned short*)(ws + 16777216);  // 25.2MB: Wt -> Ktg+Ag
  unsigned short* Ktg   = (unsigned short*)(ws + 16777216);
  unsigned short* Ag    = (unsigned short*)(ws + 33554432);
  unsigned short* Wot   = (unsigned short*)(ws + 41943040);  //  8.4MB
  unsigned short* qkvb  = (unsigned short*)(ws + 50331648);  // 50.3MB
  float*          beta  = (float*)(ws + 100663296);          //  0.26MB
  float*          invd  = (float*)(ws + 100925440);          //  0.26MB
  float*          numer = (float*)(ws + 101187584);          // 33.6MB (live from scan on)
  unsigned short* Wgt16 = (unsigned short*)(ws + 101187584); // 64KB (dead before scan)
  // gchunk [32 bh][32 ch] fp32 = 4KB lives at the head of d_out; the final
  // out-projection GEMM overwrites all of d_out afterwards.
  float*          gch   = (float*)d_out;

  k_cast<<<8192, 256, 0, stream>>>(x, xb);
  k_transw<<<dim3(32, 32, 4), 256, 0, stream>>>(Wq, Wk, Wv, Wo, Wt, Wot);
  k_transg16<<<128, 256, 0, stream>>>(Wg, Wgt16);
  k_gemm<true, false><<<dim3(48, 32), 256, 0, stream>>>(
      xb, Wt, qkvb, nullptr, 4096, 6144, 2048, 2048, 6144);
  k_betaW<<<1024, 256, 0, stream>>>(xb, Wgt16, bg, beta);
  k_prep<<<dim3(32, 32), 256, 0, stream>>>(qkvb, beta, Qt, Ktg, Ag, gch);
  k_scan<<<dim3(9, 32), 256, 0, stream>>>(Qt, Ktg, Ag, qkvb, gch, numer, invd);
  k_scale<<<4096, 256, 0, stream>>>(numer, invd, numerb);
  k_gemm<false, true><<<dim3(16, 32), 256, 0, stream>>>(
      numerb, Wot, d_out, bo, 4096, 2048, 2048, 2048, 2048);
}

// Round 5
// 435.332 us; speedup vs baseline: 1.1453x; 1.0971x over previous
//
#include <hip/hip_runtime.h>

// DeltaNet fused pipeline, round 5:
//   k_cast:    x fp32 -> bf16
//   k_transw:  Wq/Wk/Wv -> Wt (N x K bf16), Wo -> Wot, Wg -> Wgt16 (z==4)
//   k_gemm:    bf16 MFMA 128x128 GEMM, BK=64, global_load_lds(16B) staging with
//              XOR bank-swizzle (lane fetches logical slot (l&7)^((l>>3)&7);
//              reader reads phys slot (kk*4+q)^(r&7)) -> 2-way banks (free)
//   k_betaW:   wave-per-row dot: beta = clip(sigmoid(xb . Wgt16[h] + bg))
//   k_prep:    G-scan + RoPE + phi + scale + K^T transpose + intra-chunk A;
//              writes gchunk[bh][ch]
//   k_scan:    sequential 32-chunk scan, state fp32 in MFMA accumulators,
//              z-state fp32 in LDS; denom = rowsum(A) + Q~.z0 fused; writes
//              numerb = bf16(numer/denom) directly. grid (8 eb, 32 bh).
//   k_gemm:    out = numerb @ Wot + bo

typedef __attribute__((ext_vector_type(8))) short short8;
typedef __attribute__((ext_vector_type(4))) float f32x4;

__device__ __forceinline__ unsigned short f2bf(float f) {
  unsigned u = __float_as_uint(f);
  u += 0x7fffu + ((u >> 16) & 1u);   // RNE
  return (unsigned short)(u >> 16);
}
__device__ __forceinline__ float bf2f(unsigned short s) {
  return __uint_as_float(((unsigned)s) << 16);
}
__device__ __forceinline__ float phi_elu1(float x) {
  return x > 0.f ? x + 1.f : expf(x);
}
// async global->LDS, 16B per lane; LDS dest = wave-uniform base + lane*16.
__device__ __forceinline__ void gl_lds16(const void* g, void* l) {
  __builtin_amdgcn_global_load_lds(
      (const __attribute__((address_space(1))) void*)g,
      (__attribute__((address_space(3))) void*)l, 16, 0, 0);
}

// ---------------- cast x -> bf16 ----------------
__global__ __launch_bounds__(256)
void k_cast(const float* __restrict__ x, unsigned short* __restrict__ xb) {
  int i = (blockIdx.x * 256 + threadIdx.x) * 4;
  float4 f = *(const float4*)(x + i);
  uint2 p;
  p.x = (unsigned)f2bf(f.x) | ((unsigned)f2bf(f.y) << 16);
  p.y = (unsigned)f2bf(f.z) | ((unsigned)f2bf(f.w) << 16);
  *(uint2*)(xb + i) = p;
}

// ---------------- transpose+cast weights ----------------
// z 0..3: W (K x N) -> (N x K) bf16. z==4: Wg (2048x16) -> Wgt16 (16x2048).
__global__ __launch_bounds__(256)
void k_transw(const float* __restrict__ Wq, const float* __restrict__ Wk,
              const float* __restrict__ Wv, const float* __restrict__ Wo,
              const float* __restrict__ Wg,
              unsigned short* __restrict__ Wt, unsigned short* __restrict__ Wot,
              unsigned short* __restrict__ Wgt16) {
  const int z = blockIdx.z;
  if (z == 4) {
    if (blockIdx.y != 0) return;
    int idx = blockIdx.x * 256 + threadIdx.x;  // 8192 threads
    int h = idx >> 9, k4 = (idx & 511) * 4;
    uint2 p;
    p.x = (unsigned)f2bf(Wg[(k4 + 0) * 16 + h]) | ((unsigned)f2bf(Wg[(k4 + 1) * 16 + h]) << 16);
    p.y = (unsigned)f2bf(Wg[(k4 + 2) * 16 + h]) | ((unsigned)f2bf(Wg[(k4 + 3) * 16 + h]) << 16);
    *(uint2*)(Wgt16 + (size_t)h * 2048 + k4) = p;
    return;
  }
  const float* W = (z == 0) ? Wq : (z == 1) ? Wk : (z == 2) ? Wv : Wo;
  unsigned short* out = (z < 3) ? (Wt + (size_t)z * 2048 * 2048) : Wot;
  __shared__ float tile[64][65];
  const int n0 = blockIdx.x * 64;
  const int k0 = blockIdx.y * 64;
  const int tx = threadIdx.x & 63;
  const int ty = threadIdx.x >> 6;
#pragma unroll
  for (int rl = 0; rl < 16; ++rl) {
    int kk = rl * 4 + ty;
    tile[kk][tx] = W[(size_t)(k0 + kk) * 2048 + n0 + tx];
  }
  __syncthreads();
#pragma unroll
  for (int rl = 0; rl < 16; ++rl) {
    int nn = rl * 4 + ty;
    out[(size_t)(n0 + nn) * 2048 + k0 + tx] = f2bf(tile[tx][nn]);
  }
}

// ---------------- beta: wave-per-row bf16 dot + sigmoid + clip ----------------
__global__ __launch_bounds__(256)
void k_betaW(const unsigned short* __restrict__ xb, const unsigned short* __restrict__ Wgt16,
             const float* __restrict__ bg, float* __restrict__ beta) {
  const int w = threadIdx.x >> 6;
  const int lane = threadIdx.x & 63;
  const int m = blockIdx.x * 4 + w;
  const int h = lane & 15, kq = lane >> 4;
  const unsigned short* xr = xb + (size_t)m * 2048 + kq * 512;
  const unsigned short* wr = Wgt16 + (size_t)h * 2048 + kq * 512;
  float acc = 0.f;
#pragma unroll 8
  for (int i = 0; i < 64; ++i) {
    short8 xv = *(const short8*)(xr + i * 8);
    short8 wv = *(const short8*)(wr + i * 8);
#pragma unroll
    for (int j = 0; j < 8; ++j)
      acc = fmaf(bf2f((unsigned short)xv[j]), bf2f((unsigned short)wv[j]), acc);
  }
  acc += __shfl_xor(acc, 16, 64);
  acc += __shfl_xor(acc, 32, 64);
  if (lane < 16) {
    float v = acc + bg[h];
    float bv = 1.f / (1.f + expf(-v));
    beta[(size_t)m * 16 + h] = fminf(fmaxf(bv, 0.8f), 0.9995f);
  }
}

// ---------------- bf16 MFMA GEMM: C[M,N] = A[M,K] @ Bt[N,K]^T ----------------
// BK=64, swizzled global_load_lds staging.
template <bool OUT_BF16, bool ADD_BIAS>
__global__ __launch_bounds__(256)
void k_gemm(const unsigned short* __restrict__ A, const unsigned short* __restrict__ Bt,
            void* __restrict__ Cptr, const float* __restrict__ bias,
            int M, int N, int K, int ldA, int ldC) {
  __shared__ __align__(16) unsigned short As[128][64];  // 16KB
  __shared__ __align__(16) unsigned short Bs[128][64];  // 16KB
  const int tid = threadIdx.x;
  const int n0 = blockIdx.x * 128;
  const int m0 = blockIdx.y * 128;
  const int lane = tid & 63;
  const int w = tid >> 6;
  const int wm = w >> 1, wn = w & 1;
  const int q = lane >> 4, r = lane & 15;

  // staging: inst i (0..3), wave w, lane l:
  //   LDS byte = i*4096 + w*1024 + l*16  => row R = i*32 + w*8 + (l>>3),
  //   phys slot = l&7.  Logical col slot fetched: (l&7) ^ ((l>>3)&7).
  const int srow0 = w * 8 + (lane >> 3);              // R for inst 0
  const int scol = ((lane & 7) ^ ((lane >> 3) & 7)) * 8;  // swizzled logical col (shorts)

  f32x4 acc[4][4];
#pragma unroll
  for (int i = 0; i < 4; ++i)
#pragma unroll
    for (int j = 0; j < 4; ++j) acc[i][j] = (f32x4){0.f, 0.f, 0.f, 0.f};

  const unsigned short* A0 = A + (size_t)(m0 + srow0) * ldA + scol;
  const unsigned short* B0 = Bt + (size_t)(n0 + srow0) * K + scol;
  unsigned short* lA = &As[srow0][(lane & 7) * 8];
  unsigned short* lB = &Bs[srow0][(lane & 7) * 8];

  // reader phys slot per row r: (kk*4+q) ^ (r&7)
  const int rsw = r & 7;

  for (int kt = 0; kt < K; kt += 64) {
    __syncthreads();
#pragma unroll
    for (int i = 0; i < 4; ++i) {
      gl_lds16(A0 + (size_t)i * 32 * ldA + kt, lA + i * 2048);
      gl_lds16(B0 + (size_t)i * 32 * K + kt, lB + i * 2048);
    }
    __syncthreads();
#pragma unroll
    for (int kk = 0; kk < 2; ++kk) {
      const int ps = ((kk * 4 + q) ^ rsw) * 8;
      short8 af[4], bfr[4];
#pragma unroll
      for (int i = 0; i < 4; ++i)
        af[i] = *(const short8*)&As[wm * 64 + i * 16 + r][ps];
#pragma unroll
      for (int j = 0; j < 4; ++j)
        bfr[j] = *(const short8*)&Bs[wn * 64 + j * 16 + r][ps];
#pragma unroll
      for (int i = 0; i < 4; ++i)
#pragma unroll
        for (int j = 0; j < 4; ++j)
          acc[i][j] = __builtin_amdgcn_mfma_f32_16x16x32_bf16(af[i], bfr[j], acc[i][j], 0, 0, 0);
    }
  }
#pragma unroll
  for (int i = 0; i < 4; ++i) {
#pragma unroll
    for (int j = 0; j < 4; ++j) {
#pragma unroll
      for (int rr = 0; rr < 4; ++rr) {
        int mi = m0 + wm * 64 + i * 16 + q * 4 + rr;
        int ni = n0 + wn * 64 + j * 16 + r;
        float val = acc[i][j][rr];
        if (ADD_BIAS) val += bias[ni];
        if (OUT_BF16)
          ((unsigned short*)Cptr)[(size_t)mi * ldC + ni] = f2bf(val);
        else
          ((float*)Cptr)[(size_t)mi * ldC + ni] = val;
      }
    }
  }
}

// ---------------- prep: G-scan + RoPE + phi + scale + transpose + intra-chunk A ----------------
__global__ __launch_bounds__(256)
void k_prep(const unsigned short* __restrict__ qkv, const float* __restrict__ beta,
            unsigned short* __restrict__ Qt, unsigned short* __restrict__ Ktg,
            unsigned short* __restrict__ Ag, float* __restrict__ gch) {
  const int ch = blockIdx.x;
  const int bh = blockIdx.y;
  const int b = bh >> 4, h = bh & 15;
  const int tid = threadIdx.x;
  const int t0 = ch * 64;

  __shared__ float Gs[64];
  __shared__ unsigned short Qs[64][136];
  __shared__ unsigned short Ks[64][136];

  if (tid < 64) {
    float bb = beta[((size_t)(b * 2048 + t0 + tid)) * 16 + h];
#pragma unroll
    for (int off = 1; off < 64; off <<= 1) {
      float o = __shfl_up(bb, off, 64);
      if (tid >= off) bb *= o;
    }
    Gs[tid] = bb;
    if (tid == 63) gch[bh * 32 + ch] = bb;
  }
  __syncthreads();

  const int dgl = tid & 7;
  float invf[8];
#pragma unroll
  for (int j = 0; j < 8; ++j)
    invf[j] = expf((float)(dgl * 8 + j) * -0.14391156831212787f);  // 10000^(-e/64)

  int s = tid >> 3;
#pragma unroll
  for (int rep = 0; rep < 2; ++rep, s += 32) {
    size_t row = ((size_t)(b * 2048 + t0 + s)) * 6144 + (size_t)h * 128;
    short8 qlo = *(const short8*)(qkv + row + dgl * 8);
    short8 qhi = *(const short8*)(qkv + row + 64 + dgl * 8);
    short8 klo = *(const short8*)(qkv + row + 2048 + dgl * 8);
    short8 khi = *(const short8*)(qkv + row + 2048 + 64 + dgl * 8);
    float g = Gs[s];
    float ig = 1.f / g;
    float tg = (float)(t0 + s);
    short8 oql, oqh, okl, okh;
#pragma unroll
    for (int j = 0; j < 8; ++j) {
      float sn, cs;
      __sincosf(tg * invf[j], &sn, &cs);
      float qe = bf2f((unsigned short)qlo[j]), qo = bf2f((unsigned short)qhi[j]);
      float a0 = qe * cs - qo * sn, a1 = qe * sn + qo * cs;
      oql[j] = (short)f2bf(phi_elu1(a0) * g);
      oqh[j] = (short)f2bf(phi_elu1(a1) * g);
      float ke = bf2f((unsigned short)klo[j]), ko = bf2f((unsigned short)khi[j]);
      a0 = ke * cs - ko * sn;
      a1 = ke * sn + ko * cs;
      okl[j] = (short)f2bf(phi_elu1(a0) * ig);
      okh[j] = (short)f2bf(phi_elu1(a1) * ig);
    }
    size_t qbase = (((size_t)bh * 32 + ch) * 64 + s) * 128;
    *(short8*)(Qt + qbase + dgl * 8) = oql;
    *(short8*)(Qt + qbase + 64 + dgl * 8) = oqh;
    *(short8*)&Qs[s][dgl * 8] = oql;
    *(short8*)&Qs[s][64 + dgl * 8] = oqh;
    *(short8*)&Ks[s][dgl * 8] = okl;
    *(short8*)&Ks[s][64 + dgl * 8] = okh;
  }
  __syncthreads();

  {
    const int d = tid >> 1, sh = tid & 1;
    unsigned pk[16];
#pragma unroll
    for (int i = 0; i < 16; ++i)
      pk[i] = (unsigned)Ks[sh * 32 + 2 * i][d] | ((unsigned)Ks[sh * 32 + 2 * i + 1][d] << 16);
    unsigned short* kr = Ktg + ((size_t)bh * 32 + ch) * 8192 + (size_t)d * 64 + sh * 32;
#pragma unroll
    for (int i = 0; i < 4; ++i)
      *(uint4*)(kr + i * 8) = *(uint4*)&pk[i * 4];
  }

  {
    const int lane = tid & 63;
    const int w = tid >> 6;
    const int q = lane >> 4, r = lane & 15;
    f32x4 acc[4];
#pragma unroll
    for (int nt = 0; nt < 4; ++nt) acc[nt] = (f32x4){0.f, 0.f, 0.f, 0.f};
#pragma unroll
    for (int kk = 0; kk < 4; ++kk) {
      short8 af = *(const short8*)&Qs[w * 16 + r][kk * 32 + q * 8];
#pragma unroll
      for (int nt = 0; nt < 4; ++nt) {
        short8 bf = *(const short8*)&Ks[nt * 16 + r][kk * 32 + q * 8];
        acc[nt] = __builtin_amdgcn_mfma_f32_16x16x32_bf16(af, bf, acc[nt], 0, 0, 0);
      }
    }
    unsigned short* Agp = Ag + ((size_t)bh * 32 + ch) * 4096;
#pragma unroll
    for (int nt = 0; nt < 4; ++nt) {
#pragma unroll
      for (int rr = 0; rr < 4; ++rr) {
        int t_l = w * 16 + q * 4 + rr;
        int s_l = nt * 16 + r;
        float val = (s_l <= t_l) ? acc[nt][rr] : 0.f;
        Agp[t_l * 64 + s_l] = f2bf(val);
      }
    }
  }
}

// ---------------- chunk scan with fused denominator ----------------
// grid (8 eb, 32 bh). z-state fp32 in LDS (double-buffered).
__global__ __launch_bounds__(256)
void k_scan(const unsigned short* __restrict__ Qt, const unsigned short* __restrict__ Ktg,
            const unsigned short* __restrict__ Ag, const unsigned short* __restrict__ qkv,
            const float* __restrict__ gch, unsigned short* __restrict__ numerb) {
  const int eb = blockIdx.x;
  const int bh = blockIdx.y;
  const int b = bh >> 4, h = bh & 15;
  const int tid = threadIdx.x;
  const int lane = tid & 63;
  const int w = tid >> 6;
  const int q = lane >> 4, r = lane & 15;
  const int e0 = eb * 16;

  __shared__ unsigned short Qs[64][136];
  __shared__ unsigned short Kts[128][72];
  __shared__ unsigned short As[64][72];
  __shared__ unsigned short Vt[16][72];
  __shared__ unsigned short SbT[16][136];      // state readout, transposed [e][d]
  __shared__ __align__(16) float zbuf[2][128]; // z-state fp32, double-buffered

  f32x4 S_acc[2];
  S_acc[0] = (f32x4){0.f, 0.f, 0.f, 0.f};
  S_acc[1] = (f32x4){0.f, 0.f, 0.f, 0.f};
  if (tid < 128) zbuf[0][tid] = 0.f;

  for (int ch = 0; ch < 32; ++ch) {
    const int cur = ch & 1, nxt = cur ^ 1;
    __syncthreads();
    {
      const unsigned short* Qg = Qt + ((size_t)bh * 32 + ch) * 8192;
#pragma unroll
      for (int i = 0; i < 4; ++i) {
        int c = tid + i * 256;
        int ss = c >> 4, dg = c & 15;
        *(int4*)&Qs[ss][dg * 8] = *(const int4*)(Qg + ss * 128 + dg * 8);
      }
      const unsigned short* Kg = Ktg + ((size_t)bh * 32 + ch) * 8192;
#pragma unroll
      for (int i = 0; i < 4; ++i) {
        int c = tid + i * 256;
        int d = c >> 3, sg = c & 7;
        *(int4*)&Kts[d][sg * 8] = *(const int4*)(Kg + d * 64 + sg * 8);
      }
      const unsigned short* Agp = Ag + ((size_t)bh * 32 + ch) * 4096;
#pragma unroll
      for (int i = 0; i < 2; ++i) {
        int c = tid + i * 256;
        int t_l = c >> 3, sg = c & 7;
        *(int4*)&As[t_l][sg * 8] = *(const int4*)(Agp + t_l * 64 + sg * 8);
      }
      {
        int ss = tid >> 2, e4 = tid & 3;
        const unsigned short* vp =
            qkv + ((size_t)(b * 2048 + ch * 64 + ss)) * 6144 + 4096 + h * 128 + e0 + e4 * 4;
        uint2 vv = *(const uint2*)vp;
        const unsigned short* pv = (const unsigned short*)&vv;
#pragma unroll
        for (int j = 0; j < 4; ++j) Vt[e4 * 4 + j][ss] = pv[j];
      }
#pragma unroll
      for (int i = 0; i < 2; ++i)
#pragma unroll
        for (int rr = 0; rr < 4; ++rr)
          SbT[r][(2 * w + i) * 16 + q * 4 + rr] = f2bf(S_acc[i][rr]);
    }
    __syncthreads();

    const float gc = gch[bh * 32 + ch];

    // numer rows w*16..w*16+15: Qt @ S0 + A @ V ; denom = rowsum(A) + Qt . z0
    f32x4 nacc = (f32x4){0.f, 0.f, 0.f, 0.f};
    float dsum = 0.f;
#pragma unroll
    for (int kk = 0; kk < 4; ++kk) {
      short8 af = *(const short8*)&Qs[w * 16 + r][kk * 32 + q * 8];
      short8 bf = *(const short8*)&SbT[r][kk * 32 + q * 8];
      nacc = __builtin_amdgcn_mfma_f32_16x16x32_bf16(af, bf, nacc, 0, 0, 0);
      const float* zp = &zbuf[cur][kk * 32 + q * 8];
      float4 z0a = *(const float4*)zp;
      float4 z0b = *(const float4*)(zp + 4);
      dsum = fmaf(bf2f((unsigned short)af[0]), z0a.x, dsum);
      dsum = fmaf(bf2f((unsigned short)af[1]), z0a.y, dsum);
      dsum = fmaf(bf2f((unsigned short)af[2]), z0a.z, dsum);
      dsum = fmaf(bf2f((unsigned short)af[3]), z0a.w, dsum);
      dsum = fmaf(bf2f((unsigned short)af[4]), z0b.x, dsum);
      dsum = fmaf(bf2f((unsigned short)af[5]), z0b.y, dsum);
      dsum = fmaf(bf2f((unsigned short)af[6]), z0b.z, dsum);
      dsum = fmaf(bf2f((unsigned short)af[7]), z0b.w, dsum);
    }
    short8 vf[2];
#pragma unroll
    for (int kk = 0; kk < 2; ++kk) {
      vf[kk] = *(const short8*)&Vt[r][kk * 32 + q * 8];
      short8 af = *(const short8*)&As[w * 16 + r][kk * 32 + q * 8];
      nacc = __builtin_amdgcn_mfma_f32_16x16x32_bf16(af, vf[kk], nacc, 0, 0, 0);
#pragma unroll
      for (int j = 0; j < 8; ++j) dsum += bf2f((unsigned short)af[j]);
    }
    // complete denom for row w*16+r, invert, broadcast to acc-lanes
    dsum += __shfl_xor(dsum, 16, 64);
    dsum += __shfl_xor(dsum, 32, 64);
    float inv = 1.f / (dsum + 1e-6f);
#pragma unroll
    for (int rr = 0; rr < 4; ++rr) {
      float inv_r = __shfl(inv, q * 4 + rr, 64);
      int t_l = w * 16 + q * 4 + rr;
      size_t m = (size_t)b * 2048 + ch * 64 + t_l;
      numerb[m * 2048 + h * 128 + e0 + r] = f2bf(nacc[rr] * inv_r);
    }

    // z update: z' = gc * (z0 + rowsum_s Kts[d][s])
    {
      int d = tid >> 1, half = tid & 1;
      const unsigned short* kp = &Kts[d][half * 32];
      float zs = 0.f;
#pragma unroll
      for (int i = 0; i < 4; ++i) {
        short8 kv = *(const short8*)(kp + i * 8);
#pragma unroll
        for (int j = 0; j < 8; ++j) zs += bf2f((unsigned short)kv[j]);
      }
      zs += __shfl_xor(zs, 1, 64);
      if (half == 0) zbuf[nxt][d] = gc * (zbuf[cur][d] + zs);
    }

    // state update: S = gc * (S0 + Kt^T V)
#pragma unroll
    for (int i = 0; i < 2; ++i) {
#pragma unroll
      for (int kk = 0; kk < 2; ++kk) {
        short8 af = *(const short8*)&Kts[(2 * w + i) * 16 + r][kk * 32 + q * 8];
        S_acc[i] = __builtin_amdgcn_mfma_f32_16x16x32_bf16(af, vf[kk], S_acc[i], 0, 0, 0);
      }
#pragma unroll
      for (int rr = 0; rr < 4; ++rr) S_acc[i][rr] *= gc;
    }
  }
}

extern "C" void kernel_launch(void* const* d_in, const int* in_sizes, int n_in,
                              void* d_out, int out_size, void* d_ws, size_t ws_size,
                              hipStream_t stream) {
  const float* x  = (const float*)d_in[0];
  const float* Wq = (const float*)d_in[1];
  const float* Wk = (const float*)d_in[2];
  const float* Wv = (const float*)d_in[3];
  const float* Wg = (const float*)d_in[4];
  const float* bg = (const float*)d_in[5];
  const float* Wo = (const float*)d_in[6];
  const float* bo = (const float*)d_in[7];

  // workspace layout (bytes), total 134,742,016 (unchanged)
  char* ws = (char*)d_ws;
  unsigned short* xb    = (unsigned short*)(ws);             // 16.7MB: xb -> Qt
  unsigned short* Qt    = (unsigned short*)(ws);
  unsigned short* Wt    = (unsigned short*)(ws + 16777216);  // 25.2MB: Wt -> Ktg+Ag
  unsigned short* Ktg   = (unsigned short*)(ws + 16777216);
  unsigned short* Ag    = (unsigned short*)(ws + 33554432);
  unsigned short* Wot   = (unsigned short*)(ws + 41943040);  //  8.4MB
  unsigned short* qkvb  = (unsigned short*)(ws + 50331648);  // 50.3MB
  float*          beta  = (float*)(ws + 100663296);          //  0.26MB
  unsigned short* Wgt16 = (unsigned short*)(ws + 101187584); // 64KB (dead after betaW)
  unsigned short* numerb= (unsigned short*)(ws + 101187584); // 16.8MB bf16 (from scan on)
  // gchunk [32 bh][32 ch] fp32 = 4KB at head of d_out (fully overwritten by
  // the final out-projection GEMM afterwards).
  float*          gch   = (float*)d_out;

  k_cast<<<8192, 256, 0, stream>>>(x, xb);
  k_transw<<<dim3(32, 32, 5), 256, 0, stream>>>(Wq, Wk, Wv, Wo, Wg, Wt, Wot, Wgt16);
  k_gemm<true, false><<<dim3(48, 32), 256, 0, stream>>>(
      xb, Wt, qkvb, nullptr, 4096, 6144, 2048, 2048, 6144);
  k_betaW<<<1024, 256, 0, stream>>>(xb, Wgt16, bg, beta);
  k_prep<<<dim3(32, 32), 256, 0, stream>>>(qkvb, beta, Qt, Ktg, Ag, gch);
  k_scan<<<dim3(8, 32), 256, 0, stream>>>(Qt, Ktg, Ag, qkvb, gch, numerb);
  k_gemm<false, true><<<dim3(16, 32), 256, 0, stream>>>(
      numerb, Wot, d_out, bo, 4096, 2048, 2048, 2048, 2048);
}